// Round 1
// 64.177 us; speedup vs baseline: 1.0172x; 1.0172x over previous
//
#include <hip/hip_runtime.h>
#include <stdint.h>

#define N_ATOMS 8192
#define KNB 32            // MAX_NEIGHBORS
#define CUTOFF_F 5.0f
#define N_MOLS 64
#define CAP 256           // max supported molecule size (Binomial(8192,1/64): P(>195) ~ 1e-7; validated R1/R2)
#define WPB 4             // atoms (waves) per 256-thread block

// Single-wave LDS producer->consumer sync: lanes are lockstep and the LDS
// pipe is in-order per wave; the asm memory clobber stops compiler
// reordering, lgkmcnt(0) drains outstanding DS ops, sched_barrier pins it
// (guide rule #18).
__device__ __forceinline__ void wave_lds_fence() {
    asm volatile("s_waitcnt lgkmcnt(0)" ::: "memory");
    __builtin_amdgcn_sched_barrier(0);
}

// Fused kernel: one 64-lane wave per atom, 4 atoms per 256-thread block.
// Phase 0: in-wave molecule-range detection on the sorted batch array
//          (ballot over 64-wide coalesced chunks; replaces the separate
//          mol_ranges kernel + its device-wide dependency edge).
// Phase 1: candidate scan, wave-compacting valid (dist_bits<<32|j) keys
//          into LDS.
// Phase 2: exact rank selection (#{strictly smaller} == output slot,
//          identical to jax.lax.top_k stable order).
// Phase 3: coalesced 32-lane output write; pads are self-edges -> vec==0.
__global__ __launch_bounds__(64 * WPB) void radius_graph_fused(
    const float* __restrict__ pos, const int* __restrict__ batch,
    float* __restrict__ out)
{
    const int w    = threadIdx.x >> 6;     // wave id within block
    const int lane = threadIdx.x & 63;
    const int i    = blockIdx.x * WPB + w; // atom handled by this wave

    __shared__ uint64_t list[WPB][CAP];
    __shared__ int      win [WPB][KNB];

    const int b = batch[i];                // wave-uniform

    // ---- Phase 0: molecule range via ballot-scan (batch sorted) ----
    // Backward: find last index < i with batch != b; start is one past it.
    int start = 0;
    {
        int base = i - 64;
        #pragma unroll 1
        for (int s = 0; s < CAP / 64; ++s) {
            const int idx = base + lane;
            const int v   = (idx >= 0) ? batch[idx] : ~b;   // OOB marks boundary
            const unsigned long long m = __ballot(v != b);
            if (m) { start = base + 63 - (int)__builtin_clzll(m) + 1; break; }
            base -= 64;
        }
    }
    // Forward: find first index > i with batch != b; that's end.
    int end = N_ATOMS;
    {
        int base = i + 1;
        #pragma unroll 1
        for (int s = 0; s < CAP / 64; ++s) {
            const int idx = base + lane;
            const int v   = (idx < N_ATOMS) ? batch[idx] : ~b; // OOB marks boundary
            const unsigned long long m = __ballot(v != b);
            if (m) { end = base + (int)__builtin_ctzll(m); break; }
            base += 64;
        }
    }

    const float xi = pos[3 * i], yi = pos[3 * i + 1], zi = pos[3 * i + 2];
    const float sqi = xi * xi + yi * yi + zi * zi;

    // ---- Phase 1: candidate scan + wave compaction into LDS ----
    int cnt = 0;                       // wave-uniform valid count
    #pragma unroll
    for (int q = 0; q < 4; ++q) {
        const int jbase = start + (q << 6);
        if (jbase >= end) break;       // uniform exit: most molecules need q<2
        const int j = jbase + lane;
        bool valid = false; uint64_t key = 0;
        if (j < end && j != i) {
            const float xj = pos[3 * j], yj = pos[3 * j + 1], zj = pos[3 * j + 2];
            const float sqj = xj * xj + yj * yj + zj * zj;
            const float dot = xi * xj + yi * yj + zi * zj;
            const float d2  = (sqi + sqj) - 2.0f * dot;     // reference's gram trick
            const float dist = sqrtf(fmaxf(d2, 0.0f));
            if (dist <= CUTOFF_F) {
                valid = true;
                key = ((uint64_t)__float_as_uint(dist) << 32) | (uint32_t)j;
            }
        }
        const unsigned long long m = __ballot(valid);
        if (valid)
            list[w][cnt + __popcll(m & ((1ULL << lane) - 1ULL))] = key;
        cnt += __popcll(m);
    }

    if (lane < KNB) win[w][lane] = i;  // default pad: self-edge
    wave_lds_fence();                  // list/win writes visible to whole wave

    // ---- Phase 2: exact rank selection ----
    const int C = cnt;
    for (int t = lane; t < C; t += 64) {
        const uint64_t my = list[w][t];
        int r = 0;
        #pragma unroll 4
        for (int u = 0; u < C; ++u) r += (list[w][u] < my) ? 1 : 0;  // broadcast reads
        if (r < KNB) win[w][r] = (int)(uint32_t)(my & 0xFFFFFFFFu);
    }
    wave_lds_fence();                  // win writes visible before readback

    // ---- Phase 3: coalesced output write ----
    if (lane < KNB) {
        const int dst = win[w][lane];
        const long long NK = (long long)N_ATOMS * KNB;
        const long long e  = (long long)i * KNB + lane;
        out[e]      = (float)i;
        out[NK + e] = (float)dst;
        // real edge: pos[dst]-pos[i]; pad: dst==i -> exactly 0.0
        out[2 * NK + 3 * e]     = pos[3 * dst]     - xi;
        out[2 * NK + 3 * e + 1] = pos[3 * dst + 1] - yi;
        out[2 * NK + 3 * e + 2] = pos[3 * dst + 2] - zi;
        out[5 * NK + e] = (lane < C) ? 1.0f : 0.0f;
    }
}

extern "C" void kernel_launch(void* const* d_in, const int* in_sizes, int n_in,
                              void* d_out, int out_size, void* d_ws, size_t ws_size,
                              hipStream_t stream) {
    const float* pos   = (const float*)d_in[0];   // [8192, 3] f32
    const int*   batch = (const int*)d_in[1];     // [8192] i32, sorted
    float*       out   = (float*)d_out;           // 6*N*K floats
    (void)d_ws; (void)ws_size;                     // workspace no longer needed

    radius_graph_fused<<<N_ATOMS / WPB, 64 * WPB, 0, stream>>>(pos, batch, out);
}